// Round 14
// baseline (485.304 us; speedup 1.0000x reference)
//
#include <hip/hip_runtime.h>
#include <hip/hip_bf16.h>
#include <math.h>

// ---------------------------------------------------------------------------
// CapsuleNet forward. Round 14: conv1 re-tiled to 2 waves x (4M x 6N)
// (0.417 KB LDS per MFMA, 4 blocks/CU); iteration-0 softmax skipped in
// routing (logits==0 -> exactly uniform); classes fused into fc1.
// ---------------------------------------------------------------------------

#define NB 32  // batch

typedef _Float16 f16;
typedef f16 f16x2 __attribute__((ext_vector_type(2)));
typedef f16 f16x4 __attribute__((ext_vector_type(4)));
typedef f16 f16x8 __attribute__((ext_vector_type(8)));
typedef float f32x4 __attribute__((ext_vector_type(4)));

// byte offset into a [row][32 f16] LDS tile (64B rows), 16B slot q in 0..3
__device__ __forceinline__ int swz(int row, int q) {
  return row * 64 + ((q * 16) ^ (((row >> 1) & 3) << 4));
}

// ---------- weight prep: both convs in one dispatch --------------------------
__global__ __launch_bounds__(256) void wprep_kernel(
    const float* __restrict__ w1, const float* __restrict__ w2,
    f16* __restrict__ wo1, f16* __restrict__ wo2) {
  __shared__ f16 tile[256][82];
  int bi = blockIdx.x;
  const float* src;
  f16* dst;
  if (bi < 256) {
    src = w1 + (size_t)bi * 20736;
    dst = wo1 + bi * 256;
  } else {
    src = w2 + (size_t)(bi - 256) * 20736;
    dst = wo2 + (bi - 256) * 256;
  }
  int t = threadIdx.x;
  for (int j = t; j < 20736; j += 256) {
    int r = j / 81, c = j - r * 81;
    tile[r][c] = (f16)src[j];
  }
  __syncthreads();
  f16* d = dst + t;
  for (int tap = 0; tap < 81; ++tap)
    d[(size_t)tap * 65536] = tile[t][tap];
}

// ---------- conv0: x[32][1][61][61] -> h0f[32][756][256] f16, k9 s2, relu ---
__global__ __launch_bounds__(256) void conv0_kernel(
    const float* __restrict__ x, const float* __restrict__ w,
    const float* __restrict__ bias, f16* __restrict__ outf) {
  int b = blockIdx.x, ocg = blockIdx.y, z = blockIdx.z;  // grid (32, 8, 2)
  __shared__ float img[61 * 61];
  __shared__ __align__(16) float wl[81][32];  // [k][oc]
  int t = threadIdx.x;
  for (int i = t; i < 61 * 61; i += 256) img[i] = x[b * 3721 + i];
  for (int i = t; i < 81 * 32; i += 256) {
    int k = i >> 5, oc = i & 31;
    wl[k][oc] = w[(ocg * 32 + oc) * 81 + k];
  }
  __syncthreads();
  int ocs = (t & 7) * 4;  // 8 subgroups * 4 oc
  int pg  = t >> 3;       // 32 position groups
  int oc0 = ocg * 32 + ocs;
  float b0 = bias[oc0 + 0], b1 = bias[oc0 + 1], b2 = bias[oc0 + 2],
        b3 = bias[oc0 + 3];
  for (int p = pg + z * 32; p < 729; p += 64) {
    int oh = p / 27, ow = p - oh * 27;
    float a0 = 0.f, a1 = 0.f, a2 = 0.f, a3 = 0.f;
    const float* ib = &img[oh * 2 * 61 + ow * 2];
#pragma unroll
    for (int kh = 0; kh < 9; ++kh) {
#pragma unroll
      for (int kw = 0; kw < 9; ++kw) {
        float v = ib[kh * 61 + kw];
        const float4 wv =
            *reinterpret_cast<const float4*>(&wl[kh * 9 + kw][ocs]);
        a0 += v * wv.x; a1 += v * wv.y; a2 += v * wv.z; a3 += v * wv.w;
      }
    }
    int po = oh * 28 + ow;
    f16x4 hv;
    hv[0] = (f16)fmaxf(a0 + b0, 0.f);
    hv[1] = (f16)fmaxf(a1 + b1, 0.f);
    hv[2] = (f16)fmaxf(a2 + b2, 0.f);
    hv[3] = (f16)fmaxf(a3 + b3, 0.f);
    *(f16x4*)&outf[((size_t)b * 756 + po) * 256 + oc0] = hv;
  }
}

// ---------- conv1 MFMA: h0f -> part1[4][32][384][256] f16 -------------------
// 1D grid 1024, XCD-partitioned decode (R13). 128 thr = 2 waves; each wave
// 4 Mfrag x 6 Nfrag (96 pos). 40448 B LDS -> 4 blocks/CU (8 waves).
__global__ __launch_bounds__(128, 2) void conv1_mfma(
    const f16* __restrict__ xin,  // [32][756][256]
    const f16* __restrict__ wA,   // [81][256][256]
    f16* __restrict__ part) {     // [4][32][384][256]
  int f = blockIdx.x;            // 0..1023
  int v = f & 7, j = f >> 3;     // v: virtual XCD, j: 0..127
  int slice = v * 2 + (j >> 6);  // 0..15 (A-slice)
  int within = j & 63;
  int ph = within >> 5, b = within & 31;
  int ocg = slice & 3, ksp = slice >> 2;
  __shared__ __align__(16) f16 blds[504 * 32];    // 32256 B, swizzled rows
  __shared__ __align__(16) f16 alds[2][64 * 32];  // 8192 B, swizzled
  int t = threadIdx.x;
  int w = t >> 6, lane = t & 63, kg = lane >> 4, ln = lane & 15;
  int row0 = ph * 252;
  int prow[6];
#pragma unroll
  for (int nf = 0; nf < 6; ++nf) {
    int n = ph * 192 + w * 96 + nf * 16 + ln;  // [0,384)
    int oh = n / 20, ow = n - oh * 20;
    if (oh > 18) oh = 18;  // garbage rows clamp (stay in staged window)
    if (ow > 18) ow = 18;
    prow[nf] = oh * 28 + ow - row0;  // in [0,270]; +shift<=502 < 504
  }
  f32x4 acc[4][6];
#pragma unroll
  for (int m = 0; m < 4; ++m)
#pragma unroll
    for (int nf = 0; nf < 6; ++nf) acc[m][nf] = (f32x4){0.f, 0.f, 0.f, 0.f};

  const f16* xb = xin + (size_t)b * 756 * 256 + ksp * 64;
  const f16* ab = wA + (size_t)(ocg * 64) * 256 + ksp * 64;
  for (int icc = 0; icc < 2; ++icc) {
    __syncthreads();  // all reads of blds/alds from previous icc done
    for (int i = t; i < 2016; i += 128) {  // 504 rows x 4 slots
      int p = i >> 2, q = i & 3;
      f16x8 val =
          *(const f16x8*)(xb + (size_t)(row0 + p) * 256 + icc * 32 + q * 8);
      *(f16x8*)((char*)blds + swz(p, q)) = val;
    }
#pragma unroll
    for (int i = t; i < 256; i += 128) {  // stage A tap 0
      int aoc = i >> 2, aq = i & 3;
      f16x8 val =
          *(const f16x8*)(ab + (size_t)aoc * 256 + icc * 32 + aq * 8);
      *(f16x8*)((char*)alds[0] + swz(aoc, aq)) = val;
    }
    __syncthreads();
    for (int tap = 0; tap < 81; ++tap) {
      int cur = tap & 1;
      if (tap < 80) {  // stage A tap+1 into the other buffer
#pragma unroll
        for (int i = t; i < 256; i += 128) {
          int aoc = i >> 2, aq = i & 3;
          f16x8 val = *(const f16x8*)(ab + (size_t)(tap + 1) * 65536 +
                                      (size_t)aoc * 256 + icc * 32 + aq * 8);
          *(f16x8*)((char*)alds[cur ^ 1] + swz(aoc, aq)) = val;
        }
      }
      int kh = tap / 9, kw = tap - kh * 9;
      int shift = kh * 28 + kw;
      f16x8 af[4];
#pragma unroll
      for (int m = 0; m < 4; ++m)
        af[m] = *(const f16x8*)((const char*)alds[cur] + swz(m * 16 + ln, kg));
      f16x8 bf[6];
#pragma unroll
      for (int nf = 0; nf < 6; ++nf)
        bf[nf] =
            *(const f16x8*)((const char*)blds + swz(prow[nf] + shift, kg));
#pragma unroll
      for (int m = 0; m < 4; ++m)
#pragma unroll
        for (int nf = 0; nf < 6; ++nf)
          acc[m][nf] = __builtin_amdgcn_mfma_f32_16x16x32_f16(
              af[m], bf[nf], acc[m][nf], 0, 0, 0);
      __syncthreads();  // alds[cur^1] writes visible; alds[cur] reads done
    }
  }
  f16* pout = part + ((size_t)ksp * 32 + b) * 384 * 256 + ocg * 64;
#pragma unroll
  for (int m = 0; m < 4; ++m)
#pragma unroll
    for (int nf = 0; nf < 6; ++nf) {
      int n = ph * 192 + w * 96 + nf * 16 + ln;
      int oc = m * 16 + kg * 4;
      f16x4 val;
#pragma unroll
      for (int jj = 0; jj < 4; ++jj) val[jj] = (f16)acc[m][nf][jj];
      *(f16x4*)(pout + (size_t)n * 256 + oc) = val;
    }
}

// ---------- combine conv1 partials + bias + relu -> h1f[32][380][256] f16 ---
__global__ void comb1_kernel(const f16* __restrict__ part,
                             const float* __restrict__ bias,
                             f16* __restrict__ h1f) {
  int idx = blockIdx.x * 256 + threadIdx.x;  // (b, p, ocq) : 32*380*32
  if (idx >= 32 * 380 * 32) return;
  int ocq = idx & 31, rem = idx >> 5;
  int p = rem % 380, b = rem / 380;
  float a[8];
#pragma unroll
  for (int j = 0; j < 8; ++j) a[j] = bias[ocq * 8 + j];
#pragma unroll
  for (int k = 0; k < 4; ++k) {
    f16x8 v = *(const f16x8*)&part[(((size_t)k * 32 + b) * 384 + p) * 256 +
                                   ocq * 8];
#pragma unroll
    for (int j = 0; j < 8; ++j) a[j] += (float)v[j];
  }
  f16x8 o;
#pragma unroll
  for (int j = 0; j < 8; ++j) o[j] = (f16)fmaxf(a[j], 0.f);
  *(f16x8*)&h1f[((size_t)b * 380 + p) * 256 + ocq * 8] = o;
}

// ---------- prim conv MFMA: h1f -> part2[8][32][48][256] f32 ----------------
// 1D grid 512, XCD-partitioned decode (2 A-slices per virtual XCD).
__global__ __launch_bounds__(256, 3) void prim_mfma(
    const f16* __restrict__ xin,  // h1f [32][380][256]
    const f16* __restrict__ wB,   // [81][256][256]
    float* __restrict__ part2) {  // [8][32][48][256]
  int f = blockIdx.x;            // 0..511
  int v = f & 7, j = f >> 3;     // j: 0..63
  int slice = v * 2 + (j >> 5);  // 0..15
  int b = j & 31;
  int ocg = slice & 1, ksp = slice >> 1;
  __shared__ __align__(16) f16 blds[384 * 32];     // 24576 B, swizzled
  __shared__ __align__(16) f16 alds[2][128 * 32];  // 16384 B, swizzled
  int t = threadIdx.x;
  int w = t >> 6, lane = t & 63, kg = lane >> 4, ln = lane & 15;
  int rbase[3];
#pragma unroll
  for (int nf = 0; nf < 3; ++nf) {
    int rem = nf * 16 + ln;  // [0,48)
    int oh6 = rem >> 3, ow6 = rem & 7;
    rbase[nf] = oh6 * 40 + ow6 * 2;  // +shift <= 382 < 384
  }
  f32x4 acc[2][3];
#pragma unroll
  for (int m = 0; m < 2; ++m)
#pragma unroll
    for (int nf = 0; nf < 3; ++nf) acc[m][nf] = (f32x4){0.f, 0.f, 0.f, 0.f};

  for (int i = t; i < 1536; i += 256) {  // 384 rows x 4 slots
    int pos = i >> 2, q = i & 3;
    int p = pos < 380 ? pos : pos - 20;
    f16x8 val = *(const f16x8*)(xin + ((size_t)b * 380 + p) * 256 + ksp * 32 +
                                q * 8);
    *(f16x8*)((char*)blds + swz(pos, q)) = val;
  }
  const f16* ab = wB + (size_t)(ocg * 128) * 256 + ksp * 32;
  for (int i = t; i < 512; i += 256) {  // stage A tap 0: 128 oc x 4 slots
    int oc = i >> 2, q = i & 3;
    f16x8 val = *(const f16x8*)(ab + (size_t)oc * 256 + q * 8);
    *(f16x8*)((char*)alds[0] + swz(oc, q)) = val;
  }
  __syncthreads();
  for (int tap = 0; tap < 81; ++tap) {
    int cur = tap & 1;
    if (tap < 80) {
      for (int i = t; i < 512; i += 256) {
        int oc = i >> 2, q = i & 3;
        f16x8 val = *(const f16x8*)(ab + (size_t)(tap + 1) * 65536 +
                                    (size_t)oc * 256 + q * 8);
        *(f16x8*)((char*)alds[cur ^ 1] + swz(oc, q)) = val;
      }
    }
    int kh = tap / 9, kw = tap - kh * 9;
    int shift = kh * 20 + kw;
    f16x8 af[2];
#pragma unroll
    for (int m = 0; m < 2; ++m)
      af[m] = *(const f16x8*)((const char*)alds[cur] +
                              swz((w * 2 + m) * 16 + ln, kg));
    f16x8 bf[3];
#pragma unroll
    for (int nf = 0; nf < 3; ++nf)
      bf[nf] = *(const f16x8*)((const char*)blds + swz(rbase[nf] + shift, kg));
#pragma unroll
    for (int m = 0; m < 2; ++m)
#pragma unroll
      for (int nf = 0; nf < 3; ++nf)
        acc[m][nf] = __builtin_amdgcn_mfma_f32_16x16x32_f16(
            af[m], bf[nf], acc[m][nf], 0, 0, 0);
    __syncthreads();
  }
  float* pout = part2 + ((size_t)ksp * 32 + b) * 48 * 256 + ocg * 128;
#pragma unroll
  for (int m = 0; m < 2; ++m)
#pragma unroll
    for (int nf = 0; nf < 3; ++nf) {
      int n = nf * 16 + ln;
      int oc = (w * 2 + m) * 16 + kg * 4;
      *(f32x4*)(pout + (size_t)n * 256 + oc) = acc[m][nf];
    }
}

// ---------- fused ksp-sum + bias + squash: part2 -> caps[32][1152][8] -------
__global__ __launch_bounds__(256) void combsq_kernel(
    const float* __restrict__ part2,  // [8][32][48][256]
    const float* __restrict__ bias, float* __restrict__ caps) {
  int bn = blockIdx.x;
  int b = bn / 48, n = bn - b * 48;
  int ow6 = n & 7;
  if (ow6 >= 6) return;  // garbage columns (uniform exit, before any sync)
  int oh6 = n >> 3, s = oh6 * 6 + ow6;
  __shared__ float al[256];
  int oc = threadIdx.x;
  float a = 0.f;
#pragma unroll
  for (int k = 0; k < 8; ++k)
    a += part2[(((size_t)k * 32 + b) * 48 + n) * 256 + oc];
  al[oc] = a;
  __syncthreads();
  if (oc < 32) {
    int m = oc;
    float tv[8];
    float sn = 0.f;
#pragma unroll
    for (int g = 0; g < 8; ++g) {
      float v = al[g * 32 + m] + bias[g * 32 + m];
      tv[g] = v;
      sn += v * v;
    }
    float sc = sqrtf(sn) / (1.f + sn);
#pragma unroll
    for (int g = 0; g < 8; ++g)
      caps[((size_t)b * 1152 + m * 36 + s) * 8 + g] = tv[g] * sc;
  }
}

// ---------- priors1: pri[c][b][r][o] f16 = sum_i caps[b,r,i]*W1[c,r,i,o] ----
__global__ __launch_bounds__(256) void priors1_kernel(
    const float* __restrict__ x,   // caps [32][1152][8]
    const float* __restrict__ W,   // W1 [64][1152][8][16]
    f16* __restrict__ pri) {       // [64][32][1152][16]
  int c = blockIdx.x, rt = blockIdx.y;
  int r0 = rt * 32;
  __shared__ __align__(16) float xl[32 * 32 * 8];  // [b][rl][i], 32 KB
  int t = threadIdx.x;
  for (int q = t; q < 2048; q += 256) {
    int b = q >> 6, j = q & 63;  // 64 float4 per b
    *(float4*)&xl[b * 256 + j * 4] =
        *(const float4*)&x[(size_t)b * 9216 + r0 * 8 + j * 4];
  }
  int rl = t >> 3, oq = t & 7;
  float w0[8], w1[8];
#pragma unroll
  for (int i = 0; i < 8; ++i) {
    const float2 wv = *(const float2*)&W[
        (((size_t)c * 1152 + r0 + rl) * 8 + i) * 16 + 2 * oq];
    w0[i] = wv.x; w1[i] = wv.y;
  }
  __syncthreads();
  f16* pout = pri + (size_t)c * 32 * 18432 + (r0 + rl) * 16 + 2 * oq;
#pragma unroll 4
  for (int b = 0; b < 32; ++b) {
    const float4 x0 = *(const float4*)&xl[b * 256 + rl * 8];
    const float4 x1 = *(const float4*)&xl[b * 256 + rl * 8 + 4];
    float s0 = x0.x * w0[0] + x0.y * w0[1] + x0.z * w0[2] + x0.w * w0[3] +
               x1.x * w0[4] + x1.y * w0[5] + x1.z * w0[6] + x1.w * w0[7];
    float s1 = x0.x * w1[0] + x0.y * w1[1] + x0.z * w1[2] + x0.w * w1[3] +
               x1.x * w1[4] + x1.y * w1[5] + x1.z * w1[6] + x1.w * w1[7];
    f16x2 hv; hv[0] = (f16)s0; hv[1] = (f16)s1;
    *(f16x2*)(pout + (size_t)b * 18432) = hv;
  }
}

// ---------- route1: 3 iterations; iteration 0 uses exact uniform probs ------
__global__ __launch_bounds__(512) void route1_kernel(
    const f16* __restrict__ pri,  // [64][32][1152][16]
    float* __restrict__ out) {    // [B][64][16]
  constexpr int R = 1152;
  constexpr int NREG = 36;
  int c = blockIdx.x, b = blockIdx.y;
  __shared__ float lg[R], pr[R];
  __shared__ float redA[8], redB[8];
  __shared__ float sred[8][16];
  __shared__ float vsh[17];
  int t    = threadIdx.x;
  int o    = t & 15;
  int rhi  = t >> 4;   // 0..31
  int wid  = t >> 6;   // 0..7
  int lane = t & 63;
  const f16* pb = pri + ((size_t)c * 32 + b) * (R * 16);

  float prireg[NREG];
#pragma unroll
  for (int k = 0; k < NREG; ++k)
    prireg[k] = (float)pb[(k * 32 + rhi) * 16 + o];

  // ---- iteration 0: logits == 0 -> probs exactly 1/R ----
  {
    float part = 0.f;
#pragma unroll
    for (int k = 0; k < NREG; ++k) part += prireg[k];
    part += __shfl_xor(part, 16);
    part += __shfl_xor(part, 32);
    if (lane < 16) sred[wid][lane] = part;
    __syncthreads();
    if (t < 16) {
      float sv = 0.f;
#pragma unroll
      for (int w = 0; w < 8; ++w) sv += sred[w][t];
      vsh[t] = sv / (float)R;
    }
    __syncthreads();
    if (t == 0) {
      float sn = 0.f;
#pragma unroll
      for (int oo = 0; oo < 16; ++oo) sn += vsh[oo] * vsh[oo];
      vsh[16] = sqrtf(sn) / (1.f + sn);
    }
    __syncthreads();
    float vo = vsh[o] * vsh[16];
#pragma unroll
    for (int k = 0; k < NREG; ++k) {
      float val = prireg[k] * vo;
      val += __shfl_xor(val, 1);
      val += __shfl_xor(val, 2);
      val += __shfl_xor(val, 4);
      val += __shfl_xor(val, 8);
      if (o == 0) lg[k * 32 + rhi] = val;  // first write: no init needed
    }
    __syncthreads();
  }
  // ---- iterations 1, 2 ----
  for (int it = 1; it < 3; ++it) {
    float lm = -1e30f;
    for (int r = t; r < R; r += 512) lm = fmaxf(lm, lg[r]);
#pragma unroll
    for (int s2 = 1; s2 <= 32; s2 <<= 1) lm = fmaxf(lm, __shfl_xor(lm, s2));
    if (lane == 0) redA[wid] = lm;
    __syncthreads();
    if (t == 0) {
      float m8 = redA[0];
#pragma unroll
      for (int w = 1; w < 8; ++w) m8 = fmaxf(m8, redA[w]);
      redA[0] = m8;
    }
    __syncthreads();
    float m = redA[0];
    float ls = 0.f;
    for (int r = t; r < R; r += 512) {
      float e = __expf(lg[r] - m);
      pr[r] = e;
      ls += e;
    }
#pragma unroll
    for (int s2 = 1; s2 <= 32; s2 <<= 1) ls += __shfl_xor(ls, s2);
    if (lane == 0) redB[wid] = ls;
    __syncthreads();
    if (t == 0) {
      float s8 = 0.f;
#pragma unroll
      for (int w = 0; w < 8; ++w) s8 += redB[w];
      redB[0] = s8;
    }
    __syncthreads();
    float denom = redB[0];
    float part = 0.f;
#pragma unroll
    for (int k = 0; k < NREG; ++k) part += pr[k * 32 + rhi] * prireg[k];
    part += __shfl_xor(part, 16);
    part += __shfl_xor(part, 32);
    if (lane < 16) sred[wid][lane] = part;
    __syncthreads();
    if (t < 16) {
      float sv = 0.f;
#pragma unroll
      for (int w = 0; w < 8; ++w) sv += sred[w][t];
      vsh[t] = sv / denom;
    }
    __syncthreads();
    if (t == 0) {
      float sn = 0.f;
#pragma unroll
      for (int oo = 0; oo < 16; ++oo) sn += vsh[oo] * vsh[oo];
      vsh[16] = sqrtf(sn) / (1.f + sn);
    }
    __syncthreads();
    if (it < 2) {
      float vo = vsh[o] * vsh[16];
#pragma unroll
      for (int k = 0; k < NREG; ++k) {
        float val = prireg[k] * vo;
        val += __shfl_xor(val, 1);
        val += __shfl_xor(val, 2);
        val += __shfl_xor(val, 4);
        val += __shfl_xor(val, 8);
        if (o == 0) lg[k * 32 + rhi] += val;
      }
      __syncthreads();
    }
  }
  if (t < 16) out[((size_t)b * 64 + c) * 16 + t] = vsh[t] * vsh[16];
}

// ---------- dynamic routing (routing2), iteration-0 uniform skip ------------
template <int R, int CI>
__global__ __launch_bounds__(512) void routing_kernel(
    const float* __restrict__ x,   // [B][R][CI]
    const float* __restrict__ W,   // [C][R][CI][16]
    float* __restrict__ out) {     // [B][C][16]
  constexpr int NREG = R * 16 / 512;
  int c = blockIdx.x, b = blockIdx.y;
  int C = gridDim.x;
  __shared__ float xls[R * CI];
  extern __shared__ float rdyn[];
  float* lg = rdyn;
  float* pr = rdyn + R;
  __shared__ float redA[8], redB[8];
  __shared__ float sred[8][16];
  __shared__ float vsh[17];
  int t    = threadIdx.x;
  int o    = t & 15;
  int rhi  = t >> 4;
  int wid  = t >> 6;
  int lane = t & 63;
  const float* xb = x + (size_t)b * R * CI;
  const float* Wc = W + (size_t)c * R * CI * 16;

  for (int i = t; i < R * CI; i += 512) xls[i] = xb[i];
  __syncthreads();

  float pri[NREG];
#pragma unroll
  for (int k = 0; k < NREG; ++k) {
    int r = k * 32 + rhi;
    float s = 0.f;
#pragma unroll
    for (int i = 0; i < CI; ++i)
      s += xls[r * CI + i] * Wc[((size_t)r * CI + i) * 16 + o];
    pri[k] = s;
  }

  // ---- iteration 0: uniform probs ----
  {
    float part = 0.f;
#pragma unroll
    for (int k = 0; k < NREG; ++k) part += pri[k];
    part += __shfl_xor(part, 16);
    part += __shfl_xor(part, 32);
    if (lane < 16) sred[wid][lane] = part;
    __syncthreads();
    if (t < 16) {
      float sv = 0.f;
#pragma unroll
      for (int w = 0; w < 8; ++w) sv += sred[w][t];
      vsh[t] = sv / (float)R;
    }
    __syncthreads();
    if (t == 0) {
      float sn = 0.f;
#pragma unroll
      for (int oo = 0; oo < 16; ++oo) sn += vsh[oo] * vsh[oo];
      vsh[16] = sqrtf(sn) / (1.f + sn);
    }
    __syncthreads();
    float vo = vsh[o] * vsh[16];
#pragma unroll
    for (int k = 0; k < NREG; ++k) {
      float val = pri[k] * vo;
      val += __shfl_xor(val, 1);
      val += __shfl_xor(val, 2);
      val += __shfl_xor(val, 4);
      val += __shfl_xor(val, 8);
      if (o == 0) lg[k * 32 + rhi] = val;
    }
    __syncthreads();
  }
  for (int it = 1; it < 3; ++it) {
    float lm = -1e30f;
    for (int r = t; r < R; r += 512) lm = fmaxf(lm, lg[r]);
#pragma unroll
    for (int s2 = 1; s2 <= 32; s2 <<= 1) lm = fmaxf(lm, __shfl_xor(lm, s2));
    if (lane == 0) redA[wid] = lm;
    __syncthreads();
    if (t == 0) {
      float m8 = redA[0];
#pragma unroll
      for (int w = 1; w < 8; ++w) m8 = fmaxf(m8, redA[w]);
      redA[0] = m8;
    }
    __syncthreads();
    float m = redA[0];
    float ls = 0.f;
    for (int r = t; r < R; r += 512) {
      float e = __expf(lg[r] - m);
      pr[r] = e;
      ls += e;
    }
#pragma unroll
    for (int s2 = 1; s2 <= 32; s2 <<= 1) ls += __shfl_xor(ls, s2);
    if (lane == 0) redB[wid] = ls;
    __syncthreads();
    if (t == 0) {
      float s8 = 0.f;
#pragma unroll
      for (int w = 0; w < 8; ++w) s8 += redB[w];
      redB[0] = s8;
    }
    __syncthreads();
    float denom = redB[0];
    float part = 0.f;
#pragma unroll
    for (int k = 0; k < NREG; ++k) part += pr[k * 32 + rhi] * pri[k];
    part += __shfl_xor(part, 16);
    part += __shfl_xor(part, 32);
    if (lane < 16) sred[wid][lane] = part;
    __syncthreads();
    if (t < 16) {
      float sv = 0.f;
#pragma unroll
      for (int w = 0; w < 8; ++w) sv += sred[w][t];
      vsh[t] = sv / denom;
    }
    __syncthreads();
    if (t == 0) {
      float sn = 0.f;
#pragma unroll
      for (int oo = 0; oo < 16; ++oo) sn += vsh[oo] * vsh[oo];
      vsh[16] = sqrtf(sn) / (1.f + sn);
    }
    __syncthreads();
    if (it < 2) {
      float vo = vsh[o] * vsh[16];
#pragma unroll
      for (int k = 0; k < NREG; ++k) {
        float val = pri[k] * vo;
        val += __shfl_xor(val, 1);
        val += __shfl_xor(val, 2);
        val += __shfl_xor(val, 4);
        val += __shfl_xor(val, 8);
        if (o == 0) lg[k * 32 + rhi] += val;
      }
      __syncthreads();
    }
  }
  if (t < 16) out[((size_t)b * C + c) * 16 + t] = vsh[t] * vsh[16];
}

// ---------- fused classes + fc1: norms/softmax/argmax + sparse fc1 ----------
// grid (4 ngroups, 4 bgroups); 256 thr. Block (0, by) also writes outc.
__global__ __launch_bounds__(256) void fc1cls_kernel(
    const float* __restrict__ v, const float* __restrict__ w,
    const float* __restrict__ bias, float* __restrict__ outc,
    float* __restrict__ out) {
  int n  = blockIdx.x * 256 + threadIdx.x;
  int b0 = blockIdx.y * 8;
  int t = threadIdx.x;
  __shared__ float vall[8][160];
  __shared__ float nrm[8][10];
  __shared__ int ams[8];
  for (int idx = t; idx < 1280; idx += 256) {
    int bb = idx / 160, j = idx - bb * 160;
    vall[bb][j] = v[(size_t)(b0 + bb) * 160 + j];
  }
  __syncthreads();
  if (t < 80) {
    int bb = t / 10, c = t - bb * 10;
    float sn = 0.f;
#pragma unroll
    for (int o = 0; o < 16; ++o) {
      float xv = vall[bb][c * 16 + o];
      sn += xv * xv;
    }
    nrm[bb][c] = sqrtf(sn);
  }
  __syncthreads();
  if (t < 8) {
    float m = nrm[t][0];
    int am = 0;
    for (int c = 1; c < 10; ++c)
      if (nrm[t][c] > m) { m = nrm[t][c]; am = c; }  // first-max
    ams[t] = am;
    if (blockIdx.x == 0) {
      float s = 0.f;
      float e[10];
      for (int c = 0; c < 10; ++c) { e[c] = __expf(nrm[t][c] - m); s += e[c]; }
      for (int c = 0; c < 10; ++c) outc[(b0 + t) * 10 + c] = e[c] / s;
    }
  }
  __syncthreads();
  float bv = bias[n];
#pragma unroll
  for (int bb = 0; bb < 8; ++bb) {
    int row0 = ams[bb] * 16;
    float acc = bv;
#pragma unroll
    for (int oo = 0; oo < 16; ++oo)
      acc += vall[bb][row0 + oo] * w[(size_t)(row0 + oo) * 1024 + n];
    out[(size_t)(b0 + bb) * 1024 + n] = fmaxf(acc, 0.f);
  }
}

// ---------- split-K FC: partial over K-chunk -> pbuf[kz][32][N] -------------
template <int K, int KCH>
__global__ __launch_bounds__(256) void fcsplit_kernel(
    const float* __restrict__ in, const float* __restrict__ w,
    float* __restrict__ pbuf, int N) {
  int n  = blockIdx.x * 256 + threadIdx.x;
  int b0 = blockIdx.y * 8;
  int k0 = blockIdx.z * KCH;
  __shared__ __align__(16) float inl[KCH * 8];  // [k][bb]
  for (int idx = threadIdx.x; idx < 8 * KCH; idx += 256) {
    int bb = idx / KCH, k = idx - bb * KCH;
    inl[k * 8 + bb] = in[(size_t)(b0 + bb) * K + k0 + k];
  }
  __syncthreads();
  float acc[8];
#pragma unroll
  for (int bb = 0; bb < 8; ++bb) acc[bb] = 0.f;
  for (int k = 0; k < KCH; ++k) {
    float wv = w[(size_t)(k0 + k) * N + n];
    const float4 i0 = *reinterpret_cast<const float4*>(&inl[k * 8]);
    const float4 i1 = *reinterpret_cast<const float4*>(&inl[k * 8 + 4]);
    acc[0] += i0.x * wv; acc[1] += i0.y * wv;
    acc[2] += i0.z * wv; acc[3] += i0.w * wv;
    acc[4] += i1.x * wv; acc[5] += i1.y * wv;
    acc[6] += i1.z * wv; acc[7] += i1.w * wv;
  }
#pragma unroll
  for (int bb = 0; bb < 8; ++bb)
    pbuf[((size_t)blockIdx.z * 32 + b0 + bb) * N + n] = acc[bb];
}

// ---------- combine partials + bias + activation ----------------------------
template <int KS, bool RELU, bool SIG>
__global__ void fccomb_kernel(const float* __restrict__ pbuf,
                              const float* __restrict__ bias,
                              float* __restrict__ out, int N) {
  int idx = blockIdx.x * 256 + threadIdx.x;  // b*N + n
  if (idx >= 32 * N) return;
  int b = idx / N, n = idx - b * N;
  float a = bias[n];
#pragma unroll
  for (int kz = 0; kz < KS; ++kz) a += pbuf[((size_t)kz * 32 + b) * N + n];
  if (RELU) a = fmaxf(a, 0.f);
  if (SIG)  a = 1.f / (1.f + __expf(-a));
  out[idx] = a;
}

// ---------------------------------------------------------------------------
extern "C" void kernel_launch(void* const* d_in, const int* in_sizes, int n_in,
                              void* d_out, int out_size, void* d_ws,
                              size_t ws_size, hipStream_t stream) {
  const float* x       = (const float*)d_in[0];
  const float* conv0_w = (const float*)d_in[1];
  const float* conv0_b = (const float*)d_in[2];
  const float* conv1_w = (const float*)d_in[3];
  const float* conv1_b = (const float*)d_in[4];
  const float* prim_w  = (const float*)d_in[5];
  const float* prim_b  = (const float*)d_in[6];
  const float* W1      = (const float*)d_in[7];
  const float* W2      = (const float*)d_in[8];
  const float* dec_w1  = (const float*)d_in[9];
  const float* dec_b1  = (const float*)d_in[10];
  const float* dec_w2  = (const float*)d_in[11];
  const float* dec_b2  = (const float*)d_in[12];
  const float* dec_w3  = (const float*)d_in[13];
  const float* dec_b3  = (const float*)d_in[14];
  float* out = (float*)d_out;

  // ---- persistent zone ----
  float* ws    = (float*)d_ws;
  float* caps  = ws;                    //   294,912 f  [32][1152][8]
  float* u     = caps + 294912;         //    32,768 f  [32][64][16]
  float* vc    = u + 32768;             //     5,120 f  [32][10][16]
  float* trans = vc + 5120 + 32;        // transient zone base

  // ---- transient zone: conv phase ----
  f16* wA    = (f16*)trans;             //  5,308,416 h [81][256][256]
  f16* wB    = wA + 5308416;            //  5,308,416 h (tap-81 over-read ok)
  f16* h0f   = wB + 5308416;            //  6,193,152 h [32][756][256]
  f16* h1f   = h0f + 6193152;           //  3,112,960 h [32][380][256]
  f16* part1 = h1f + 3112960;           // 12,582,912 h [4][32][384][256]
  float* part2 = (float*)part1;         //  3,145,728 f (alias part1)
  // ---- transient zone: routing phase ----
  f16* pri1  = (f16*)trans;             // 37,748,736 h [64][32][1152][16]
  // ---- transient zone: decoder phase ----
  float* d1  = trans;                   //    32,768 f
  float* d2  = d1 + 32768;              //    65,536 f
  float* pb2 = d2 + 65536;              //   262,144 f
  float* pb3 = pb2 + 262144;            // 1,048,576 f

  wprep_kernel<<<512, 256, 0, stream>>>(conv1_w, prim_w, wA, wB);

  conv0_kernel<<<dim3(NB, 8, 2), 256, 0, stream>>>(x, conv0_w, conv0_b, h0f);

  conv1_mfma<<<1024, 128, 0, stream>>>(h0f, wA, part1);
  comb1_kernel<<<1520, 256, 0, stream>>>(part1, conv1_b, h1f);

  prim_mfma<<<512, 256, 0, stream>>>(h1f, wB, part2);
  combsq_kernel<<<NB * 48, 256, 0, stream>>>(part2, prim_b, caps);

  priors1_kernel<<<dim3(64, 36), 256, 0, stream>>>(caps, W1, pri1);
  route1_kernel<<<dim3(64, NB), 512, 0, stream>>>(pri1, u);

  routing_kernel<64, 16>
      <<<dim3(10, NB), 512, 2 * 64 * sizeof(float), stream>>>(u, W2, vc);

  fc1cls_kernel<<<dim3(4, 4), 256, 0, stream>>>(vc, dec_w1, dec_b1, out, d1);

  fcsplit_kernel<1024, 256>
      <<<dim3(8, 4, 4), 256, 0, stream>>>(d1, dec_w2, pb2, 2048);
  fccomb_kernel<4, true, false>
      <<<256, 256, 0, stream>>>(pb2, dec_b2, d2, 2048);

  fcsplit_kernel<2048, 256>
      <<<dim3(16, 4, 8), 256, 0, stream>>>(d2, dec_w3, pb3, 4096);
  fccomb_kernel<8, false, true>
      <<<512, 256, 0, stream>>>(pb3, dec_b3, out + 320, 4096);
}

// Round 15
// 431.231 us; speedup vs baseline: 1.1254x; 1.1254x over previous
//
#include <hip/hip_runtime.h>
#include <hip/hip_bf16.h>
#include <math.h>

// ---------------------------------------------------------------------------
// CapsuleNet forward. Round 15: composition of measured bests —
// conv1 = R13 exact (256thr, XCD-partitioned, 119us); routing iter-0
// uniform-softmax skip (R14, bit-exact); classes+fc1 fused (R14).
// ---------------------------------------------------------------------------

#define NB 32  // batch

typedef _Float16 f16;
typedef f16 f16x2 __attribute__((ext_vector_type(2)));
typedef f16 f16x4 __attribute__((ext_vector_type(4)));
typedef f16 f16x8 __attribute__((ext_vector_type(8)));
typedef float f32x4 __attribute__((ext_vector_type(4)));

// byte offset into a [row][32 f16] LDS tile (64B rows), 16B slot q in 0..3
__device__ __forceinline__ int swz(int row, int q) {
  return row * 64 + ((q * 16) ^ (((row >> 1) & 3) << 4));
}

// ---------- weight prep: both convs in one dispatch --------------------------
__global__ __launch_bounds__(256) void wprep_kernel(
    const float* __restrict__ w1, const float* __restrict__ w2,
    f16* __restrict__ wo1, f16* __restrict__ wo2) {
  __shared__ f16 tile[256][82];
  int bi = blockIdx.x;
  const float* src;
  f16* dst;
  if (bi < 256) {
    src = w1 + (size_t)bi * 20736;
    dst = wo1 + bi * 256;
  } else {
    src = w2 + (size_t)(bi - 256) * 20736;
    dst = wo2 + (bi - 256) * 256;
  }
  int t = threadIdx.x;
  for (int j = t; j < 20736; j += 256) {
    int r = j / 81, c = j - r * 81;
    tile[r][c] = (f16)src[j];
  }
  __syncthreads();
  f16* d = dst + t;
  for (int tap = 0; tap < 81; ++tap)
    d[(size_t)tap * 65536] = tile[t][tap];
}

// ---------- conv0: x[32][1][61][61] -> h0f[32][756][256] f16, k9 s2, relu ---
__global__ __launch_bounds__(256) void conv0_kernel(
    const float* __restrict__ x, const float* __restrict__ w,
    const float* __restrict__ bias, f16* __restrict__ outf) {
  int b = blockIdx.x, ocg = blockIdx.y, z = blockIdx.z;  // grid (32, 8, 2)
  __shared__ float img[61 * 61];
  __shared__ __align__(16) float wl[81][32];  // [k][oc]
  int t = threadIdx.x;
  for (int i = t; i < 61 * 61; i += 256) img[i] = x[b * 3721 + i];
  for (int i = t; i < 81 * 32; i += 256) {
    int k = i >> 5, oc = i & 31;
    wl[k][oc] = w[(ocg * 32 + oc) * 81 + k];
  }
  __syncthreads();
  int ocs = (t & 7) * 4;  // 8 subgroups * 4 oc
  int pg  = t >> 3;       // 32 position groups
  int oc0 = ocg * 32 + ocs;
  float b0 = bias[oc0 + 0], b1 = bias[oc0 + 1], b2 = bias[oc0 + 2],
        b3 = bias[oc0 + 3];
  for (int p = pg + z * 32; p < 729; p += 64) {
    int oh = p / 27, ow = p - oh * 27;
    float a0 = 0.f, a1 = 0.f, a2 = 0.f, a3 = 0.f;
    const float* ib = &img[oh * 2 * 61 + ow * 2];
#pragma unroll
    for (int kh = 0; kh < 9; ++kh) {
#pragma unroll
      for (int kw = 0; kw < 9; ++kw) {
        float v = ib[kh * 61 + kw];
        const float4 wv =
            *reinterpret_cast<const float4*>(&wl[kh * 9 + kw][ocs]);
        a0 += v * wv.x; a1 += v * wv.y; a2 += v * wv.z; a3 += v * wv.w;
      }
    }
    int po = oh * 28 + ow;
    f16x4 hv;
    hv[0] = (f16)fmaxf(a0 + b0, 0.f);
    hv[1] = (f16)fmaxf(a1 + b1, 0.f);
    hv[2] = (f16)fmaxf(a2 + b2, 0.f);
    hv[3] = (f16)fmaxf(a3 + b3, 0.f);
    *(f16x4*)&outf[((size_t)b * 756 + po) * 256 + oc0] = hv;
  }
}

// ---------- conv1 MFMA (R13 exact): h0f -> part1[4][32][384][256] f16 -------
// 1D grid 1024, XCD-partitioned decode: virtual XCD v = f&7 owns A-slices
// {2v, 2v+1} (1.33MB, L2-resident). 256 thr = 4 waves, 4M x 3N per wave.
__global__ __launch_bounds__(256, 3) void conv1_mfma(
    const f16* __restrict__ xin,  // [32][756][256]
    const f16* __restrict__ wA,   // [81][256][256]
    f16* __restrict__ part) {     // [4][32][384][256]
  int f = blockIdx.x;            // 0..1023
  int v = f & 7, j = f >> 3;     // v: virtual XCD, j: 0..127
  int slice = v * 2 + (j >> 6);  // 0..15 (A-slice)
  int within = j & 63;
  int ph = within >> 5, b = within & 31;
  int ocg = slice & 3, ksp = slice >> 2;
  __shared__ __align__(16) f16 blds[504 * 32];    // 32256 B, swizzled rows
  __shared__ __align__(16) f16 alds[2][64 * 32];  // 8192 B, swizzled
  int t = threadIdx.x;
  int w = t >> 6, lane = t & 63, kg = lane >> 4, ln = lane & 15;
  int aoc = t >> 2, aq = t & 3;  // A staging: 64 oc x 4 slots, 1 store/thr
  int row0 = ph * 252;
  int prow[3];
#pragma unroll
  for (int nf = 0; nf < 3; ++nf) {
    int n = ph * 192 + w * 48 + nf * 16 + ln;  // [0,384)
    int oh = n / 20, ow = n - oh * 20;
    if (oh > 18) oh = 18;  // garbage rows clamp (stay in staged window)
    if (ow > 18) ow = 18;
    prow[nf] = oh * 28 + ow - row0;  // in [0,270]; +shift<=502 < 504
  }
  f32x4 acc[4][3];
#pragma unroll
  for (int m = 0; m < 4; ++m)
#pragma unroll
    for (int nf = 0; nf < 3; ++nf) acc[m][nf] = (f32x4){0.f, 0.f, 0.f, 0.f};

  const f16* xb = xin + (size_t)b * 756 * 256 + ksp * 64;
  const f16* ab = wA + (size_t)(ocg * 64 + aoc) * 256 + ksp * 64 + aq * 8;
  for (int icc = 0; icc < 2; ++icc) {
    __syncthreads();  // all reads of blds/alds from previous icc done
    for (int i = t; i < 2016; i += 256) {  // 504 rows x 4 slots
      int p = i >> 2, q = i & 3;
      f16x8 val =
          *(const f16x8*)(xb + (size_t)(row0 + p) * 256 + icc * 32 + q * 8);
      *(f16x8*)((char*)blds + swz(p, q)) = val;
    }
    {  // stage A tap 0
      f16x8 val = *(const f16x8*)(ab + icc * 32);
      *(f16x8*)((char*)alds[0] + swz(aoc, aq)) = val;
    }
    __syncthreads();
    for (int tap = 0; tap < 81; ++tap) {
      int cur = tap & 1;
      if (tap < 80) {  // stage A tap+1 into the other buffer
        f16x8 val = *(const f16x8*)(ab + (size_t)(tap + 1) * 65536 + icc * 32);
        *(f16x8*)((char*)alds[cur ^ 1] + swz(aoc, aq)) = val;
      }
      int kh = tap / 9, kw = tap - kh * 9;
      int shift = kh * 28 + kw;
      f16x8 af[4];
#pragma unroll
      for (int m = 0; m < 4; ++m)
        af[m] = *(const f16x8*)((const char*)alds[cur] + swz(m * 16 + ln, kg));
      f16x8 bf[3];
#pragma unroll
      for (int nf = 0; nf < 3; ++nf)
        bf[nf] =
            *(const f16x8*)((const char*)blds + swz(prow[nf] + shift, kg));
#pragma unroll
      for (int m = 0; m < 4; ++m)
#pragma unroll
        for (int nf = 0; nf < 3; ++nf)
          acc[m][nf] = __builtin_amdgcn_mfma_f32_16x16x32_f16(
              af[m], bf[nf], acc[m][nf], 0, 0, 0);
      __syncthreads();  // alds[cur^1] writes visible; alds[cur] reads done
    }
  }
  f16* pout = part + ((size_t)ksp * 32 + b) * 384 * 256 + ocg * 64;
#pragma unroll
  for (int m = 0; m < 4; ++m)
#pragma unroll
    for (int nf = 0; nf < 3; ++nf) {
      int n = ph * 192 + w * 48 + nf * 16 + ln;
      int oc = m * 16 + kg * 4;
      f16x4 val;
#pragma unroll
      for (int jj = 0; jj < 4; ++jj) val[jj] = (f16)acc[m][nf][jj];
      *(f16x4*)(pout + (size_t)n * 256 + oc) = val;
    }
}

// ---------- combine conv1 partials + bias + relu -> h1f[32][380][256] f16 ---
__global__ void comb1_kernel(const f16* __restrict__ part,
                             const float* __restrict__ bias,
                             f16* __restrict__ h1f) {
  int idx = blockIdx.x * 256 + threadIdx.x;  // (b, p, ocq) : 32*380*32
  if (idx >= 32 * 380 * 32) return;
  int ocq = idx & 31, rem = idx >> 5;
  int p = rem % 380, b = rem / 380;
  float a[8];
#pragma unroll
  for (int j = 0; j < 8; ++j) a[j] = bias[ocq * 8 + j];
#pragma unroll
  for (int k = 0; k < 4; ++k) {
    f16x8 v = *(const f16x8*)&part[(((size_t)k * 32 + b) * 384 + p) * 256 +
                                   ocq * 8];
#pragma unroll
    for (int j = 0; j < 8; ++j) a[j] += (float)v[j];
  }
  f16x8 o;
#pragma unroll
  for (int j = 0; j < 8; ++j) o[j] = (f16)fmaxf(a[j], 0.f);
  *(f16x8*)&h1f[((size_t)b * 380 + p) * 256 + ocq * 8] = o;
}

// ---------- prim conv MFMA: h1f -> part2[8][32][48][256] f32 ----------------
// 1D grid 512, XCD-partitioned decode (2 A-slices per virtual XCD).
__global__ __launch_bounds__(256, 3) void prim_mfma(
    const f16* __restrict__ xin,  // h1f [32][380][256]
    const f16* __restrict__ wB,   // [81][256][256]
    float* __restrict__ part2) {  // [8][32][48][256]
  int f = blockIdx.x;            // 0..511
  int v = f & 7, j = f >> 3;     // j: 0..63
  int slice = v * 2 + (j >> 5);  // 0..15
  int b = j & 31;
  int ocg = slice & 1, ksp = slice >> 1;
  __shared__ __align__(16) f16 blds[384 * 32];     // 24576 B, swizzled
  __shared__ __align__(16) f16 alds[2][128 * 32];  // 16384 B, swizzled
  int t = threadIdx.x;
  int w = t >> 6, lane = t & 63, kg = lane >> 4, ln = lane & 15;
  int rbase[3];
#pragma unroll
  for (int nf = 0; nf < 3; ++nf) {
    int rem = nf * 16 + ln;  // [0,48)
    int oh6 = rem >> 3, ow6 = rem & 7;
    rbase[nf] = oh6 * 40 + ow6 * 2;  // +shift <= 382 < 384
  }
  f32x4 acc[2][3];
#pragma unroll
  for (int m = 0; m < 2; ++m)
#pragma unroll
    for (int nf = 0; nf < 3; ++nf) acc[m][nf] = (f32x4){0.f, 0.f, 0.f, 0.f};

  for (int i = t; i < 1536; i += 256) {  // 384 rows x 4 slots
    int pos = i >> 2, q = i & 3;
    int p = pos < 380 ? pos : pos - 20;
    f16x8 val = *(const f16x8*)(xin + ((size_t)b * 380 + p) * 256 + ksp * 32 +
                                q * 8);
    *(f16x8*)((char*)blds + swz(pos, q)) = val;
  }
  const f16* ab = wB + (size_t)(ocg * 128) * 256 + ksp * 32;
  for (int i = t; i < 512; i += 256) {  // stage A tap 0: 128 oc x 4 slots
    int oc = i >> 2, q = i & 3;
    f16x8 val = *(const f16x8*)(ab + (size_t)oc * 256 + q * 8);
    *(f16x8*)((char*)alds[0] + swz(oc, q)) = val;
  }
  __syncthreads();
  for (int tap = 0; tap < 81; ++tap) {
    int cur = tap & 1;
    if (tap < 80) {
      for (int i = t; i < 512; i += 256) {
        int oc = i >> 2, q = i & 3;
        f16x8 val = *(const f16x8*)(ab + (size_t)(tap + 1) * 65536 +
                                    (size_t)oc * 256 + q * 8);
        *(f16x8*)((char*)alds[cur ^ 1] + swz(oc, q)) = val;
      }
    }
    int kh = tap / 9, kw = tap - kh * 9;
    int shift = kh * 20 + kw;
    f16x8 af[2];
#pragma unroll
    for (int m = 0; m < 2; ++m)
      af[m] = *(const f16x8*)((const char*)alds[cur] +
                              swz((w * 2 + m) * 16 + ln, kg));
    f16x8 bf[3];
#pragma unroll
    for (int nf = 0; nf < 3; ++nf)
      bf[nf] = *(const f16x8*)((const char*)blds + swz(rbase[nf] + shift, kg));
#pragma unroll
    for (int m = 0; m < 2; ++m)
#pragma unroll
      for (int nf = 0; nf < 3; ++nf)
        acc[m][nf] = __builtin_amdgcn_mfma_f32_16x16x32_f16(
            af[m], bf[nf], acc[m][nf], 0, 0, 0);
    __syncthreads();
  }
  float* pout = part2 + ((size_t)ksp * 32 + b) * 48 * 256 + ocg * 128;
#pragma unroll
  for (int m = 0; m < 2; ++m)
#pragma unroll
    for (int nf = 0; nf < 3; ++nf) {
      int n = nf * 16 + ln;
      int oc = (w * 2 + m) * 16 + kg * 4;
      *(f32x4*)(pout + (size_t)n * 256 + oc) = acc[m][nf];
    }
}

// ---------- fused ksp-sum + bias + squash: part2 -> caps[32][1152][8] -------
__global__ __launch_bounds__(256) void combsq_kernel(
    const float* __restrict__ part2,  // [8][32][48][256]
    const float* __restrict__ bias, float* __restrict__ caps) {
  int bn = blockIdx.x;
  int b = bn / 48, n = bn - b * 48;
  int ow6 = n & 7;
  if (ow6 >= 6) return;  // garbage columns (uniform exit, before any sync)
  int oh6 = n >> 3, s = oh6 * 6 + ow6;
  __shared__ float al[256];
  int oc = threadIdx.x;
  float a = 0.f;
#pragma unroll
  for (int k = 0; k < 8; ++k)
    a += part2[(((size_t)k * 32 + b) * 48 + n) * 256 + oc];
  al[oc] = a;
  __syncthreads();
  if (oc < 32) {
    int m = oc;
    float tv[8];
    float sn = 0.f;
#pragma unroll
    for (int g = 0; g < 8; ++g) {
      float v = al[g * 32 + m] + bias[g * 32 + m];
      tv[g] = v;
      sn += v * v;
    }
    float sc = sqrtf(sn) / (1.f + sn);
#pragma unroll
    for (int g = 0; g < 8; ++g)
      caps[((size_t)b * 1152 + m * 36 + s) * 8 + g] = tv[g] * sc;
  }
}

// ---------- priors1: pri[c][b][r][o] f16 = sum_i caps[b,r,i]*W1[c,r,i,o] ----
__global__ __launch_bounds__(256) void priors1_kernel(
    const float* __restrict__ x,   // caps [32][1152][8]
    const float* __restrict__ W,   // W1 [64][1152][8][16]
    f16* __restrict__ pri) {       // [64][32][1152][16]
  int c = blockIdx.x, rt = blockIdx.y;
  int r0 = rt * 32;
  __shared__ __align__(16) float xl[32 * 32 * 8];  // [b][rl][i], 32 KB
  int t = threadIdx.x;
  for (int q = t; q < 2048; q += 256) {
    int b = q >> 6, j = q & 63;  // 64 float4 per b
    *(float4*)&xl[b * 256 + j * 4] =
        *(const float4*)&x[(size_t)b * 9216 + r0 * 8 + j * 4];
  }
  int rl = t >> 3, oq = t & 7;
  float w0[8], w1[8];
#pragma unroll
  for (int i = 0; i < 8; ++i) {
    const float2 wv = *(const float2*)&W[
        (((size_t)c * 1152 + r0 + rl) * 8 + i) * 16 + 2 * oq];
    w0[i] = wv.x; w1[i] = wv.y;
  }
  __syncthreads();
  f16* pout = pri + (size_t)c * 32 * 18432 + (r0 + rl) * 16 + 2 * oq;
#pragma unroll 4
  for (int b = 0; b < 32; ++b) {
    const float4 x0 = *(const float4*)&xl[b * 256 + rl * 8];
    const float4 x1 = *(const float4*)&xl[b * 256 + rl * 8 + 4];
    float s0 = x0.x * w0[0] + x0.y * w0[1] + x0.z * w0[2] + x0.w * w0[3] +
               x1.x * w0[4] + x1.y * w0[5] + x1.z * w0[6] + x1.w * w0[7];
    float s1 = x0.x * w1[0] + x0.y * w1[1] + x0.z * w1[2] + x0.w * w1[3] +
               x1.x * w1[4] + x1.y * w1[5] + x1.z * w1[6] + x1.w * w1[7];
    f16x2 hv; hv[0] = (f16)s0; hv[1] = (f16)s1;
    *(f16x2*)(pout + (size_t)b * 18432) = hv;
  }
}

// ---------- route1: 3 iterations; iteration 0 uses exact uniform probs ------
__global__ __launch_bounds__(512) void route1_kernel(
    const f16* __restrict__ pri,  // [64][32][1152][16]
    float* __restrict__ out) {    // [B][64][16]
  constexpr int R = 1152;
  constexpr int NREG = 36;
  int c = blockIdx.x, b = blockIdx.y;
  __shared__ float lg[R], pr[R];
  __shared__ float redA[8], redB[8];
  __shared__ float sred[8][16];
  __shared__ float vsh[17];
  int t    = threadIdx.x;
  int o    = t & 15;
  int rhi  = t >> 4;   // 0..31
  int wid  = t >> 6;   // 0..7
  int lane = t & 63;
  const f16* pb = pri + ((size_t)c * 32 + b) * (R * 16);

  float prireg[NREG];
#pragma unroll
  for (int k = 0; k < NREG; ++k)
    prireg[k] = (float)pb[(k * 32 + rhi) * 16 + o];

  // ---- iteration 0: logits == 0 -> probs exactly 1/R ----
  {
    float part = 0.f;
#pragma unroll
    for (int k = 0; k < NREG; ++k) part += prireg[k];
    part += __shfl_xor(part, 16);
    part += __shfl_xor(part, 32);
    if (lane < 16) sred[wid][lane] = part;
    __syncthreads();
    if (t < 16) {
      float sv = 0.f;
#pragma unroll
      for (int w = 0; w < 8; ++w) sv += sred[w][t];
      vsh[t] = sv / (float)R;
    }
    __syncthreads();
    if (t == 0) {
      float sn = 0.f;
#pragma unroll
      for (int oo = 0; oo < 16; ++oo) sn += vsh[oo] * vsh[oo];
      vsh[16] = sqrtf(sn) / (1.f + sn);
    }
    __syncthreads();
    float vo = vsh[o] * vsh[16];
#pragma unroll
    for (int k = 0; k < NREG; ++k) {
      float val = prireg[k] * vo;
      val += __shfl_xor(val, 1);
      val += __shfl_xor(val, 2);
      val += __shfl_xor(val, 4);
      val += __shfl_xor(val, 8);
      if (o == 0) lg[k * 32 + rhi] = val;  // first write: no init needed
    }
    __syncthreads();
  }
  // ---- iterations 1, 2 ----
  for (int it = 1; it < 3; ++it) {
    float lm = -1e30f;
    for (int r = t; r < R; r += 512) lm = fmaxf(lm, lg[r]);
#pragma unroll
    for (int s2 = 1; s2 <= 32; s2 <<= 1) lm = fmaxf(lm, __shfl_xor(lm, s2));
    if (lane == 0) redA[wid] = lm;
    __syncthreads();
    if (t == 0) {
      float m8 = redA[0];
#pragma unroll
      for (int w = 1; w < 8; ++w) m8 = fmaxf(m8, redA[w]);
      redA[0] = m8;
    }
    __syncthreads();
    float m = redA[0];
    float ls = 0.f;
    for (int r = t; r < R; r += 512) {
      float e = __expf(lg[r] - m);
      pr[r] = e;
      ls += e;
    }
#pragma unroll
    for (int s2 = 1; s2 <= 32; s2 <<= 1) ls += __shfl_xor(ls, s2);
    if (lane == 0) redB[wid] = ls;
    __syncthreads();
    if (t == 0) {
      float s8 = 0.f;
#pragma unroll
      for (int w = 0; w < 8; ++w) s8 += redB[w];
      redB[0] = s8;
    }
    __syncthreads();
    float denom = redB[0];
    float part = 0.f;
#pragma unroll
    for (int k = 0; k < NREG; ++k) part += pr[k * 32 + rhi] * prireg[k];
    part += __shfl_xor(part, 16);
    part += __shfl_xor(part, 32);
    if (lane < 16) sred[wid][lane] = part;
    __syncthreads();
    if (t < 16) {
      float sv = 0.f;
#pragma unroll
      for (int w = 0; w < 8; ++w) sv += sred[w][t];
      vsh[t] = sv / denom;
    }
    __syncthreads();
    if (t == 0) {
      float sn = 0.f;
#pragma unroll
      for (int oo = 0; oo < 16; ++oo) sn += vsh[oo] * vsh[oo];
      vsh[16] = sqrtf(sn) / (1.f + sn);
    }
    __syncthreads();
    if (it < 2) {
      float vo = vsh[o] * vsh[16];
#pragma unroll
      for (int k = 0; k < NREG; ++k) {
        float val = prireg[k] * vo;
        val += __shfl_xor(val, 1);
        val += __shfl_xor(val, 2);
        val += __shfl_xor(val, 4);
        val += __shfl_xor(val, 8);
        if (o == 0) lg[k * 32 + rhi] += val;
      }
      __syncthreads();
    }
  }
  if (t < 16) out[((size_t)b * 64 + c) * 16 + t] = vsh[t] * vsh[16];
}

// ---------- dynamic routing (routing2), iteration-0 uniform skip ------------
template <int R, int CI>
__global__ __launch_bounds__(512) void routing_kernel(
    const float* __restrict__ x,   // [B][R][CI]
    const float* __restrict__ W,   // [C][R][CI][16]
    float* __restrict__ out) {     // [B][C][16]
  constexpr int NREG = R * 16 / 512;
  int c = blockIdx.x, b = blockIdx.y;
  int C = gridDim.x;
  __shared__ float xls[R * CI];
  extern __shared__ float rdyn[];
  float* lg = rdyn;
  float* pr = rdyn + R;
  __shared__ float redA[8], redB[8];
  __shared__ float sred[8][16];
  __shared__ float vsh[17];
  int t    = threadIdx.x;
  int o    = t & 15;
  int rhi  = t >> 4;
  int wid  = t >> 6;
  int lane = t & 63;
  const float* xb = x + (size_t)b * R * CI;
  const float* Wc = W + (size_t)c * R * CI * 16;

  for (int i = t; i < R * CI; i += 512) xls[i] = xb[i];
  __syncthreads();

  float pri[NREG];
#pragma unroll
  for (int k = 0; k < NREG; ++k) {
    int r = k * 32 + rhi;
    float s = 0.f;
#pragma unroll
    for (int i = 0; i < CI; ++i)
      s += xls[r * CI + i] * Wc[((size_t)r * CI + i) * 16 + o];
    pri[k] = s;
  }

  // ---- iteration 0: uniform probs ----
  {
    float part = 0.f;
#pragma unroll
    for (int k = 0; k < NREG; ++k) part += pri[k];
    part += __shfl_xor(part, 16);
    part += __shfl_xor(part, 32);
    if (lane < 16) sred[wid][lane] = part;
    __syncthreads();
    if (t < 16) {
      float sv = 0.f;
#pragma unroll
      for (int w = 0; w < 8; ++w) sv += sred[w][t];
      vsh[t] = sv / (float)R;
    }
    __syncthreads();
    if (t == 0) {
      float sn = 0.f;
#pragma unroll
      for (int oo = 0; oo < 16; ++oo) sn += vsh[oo] * vsh[oo];
      vsh[16] = sqrtf(sn) / (1.f + sn);
    }
    __syncthreads();
    float vo = vsh[o] * vsh[16];
#pragma unroll
    for (int k = 0; k < NREG; ++k) {
      float val = pri[k] * vo;
      val += __shfl_xor(val, 1);
      val += __shfl_xor(val, 2);
      val += __shfl_xor(val, 4);
      val += __shfl_xor(val, 8);
      if (o == 0) lg[k * 32 + rhi] = val;
    }
    __syncthreads();
  }
  for (int it = 1; it < 3; ++it) {
    float lm = -1e30f;
    for (int r = t; r < R; r += 512) lm = fmaxf(lm, lg[r]);
#pragma unroll
    for (int s2 = 1; s2 <= 32; s2 <<= 1) lm = fmaxf(lm, __shfl_xor(lm, s2));
    if (lane == 0) redA[wid] = lm;
    __syncthreads();
    if (t == 0) {
      float m8 = redA[0];
#pragma unroll
      for (int w = 1; w < 8; ++w) m8 = fmaxf(m8, redA[w]);
      redA[0] = m8;
    }
    __syncthreads();
    float m = redA[0];
    float ls = 0.f;
    for (int r = t; r < R; r += 512) {
      float e = __expf(lg[r] - m);
      pr[r] = e;
      ls += e;
    }
#pragma unroll
    for (int s2 = 1; s2 <= 32; s2 <<= 1) ls += __shfl_xor(ls, s2);
    if (lane == 0) redB[wid] = ls;
    __syncthreads();
    if (t == 0) {
      float s8 = 0.f;
#pragma unroll
      for (int w = 0; w < 8; ++w) s8 += redB[w];
      redB[0] = s8;
    }
    __syncthreads();
    float denom = redB[0];
    float part = 0.f;
#pragma unroll
    for (int k = 0; k < NREG; ++k) part += pr[k * 32 + rhi] * pri[k];
    part += __shfl_xor(part, 16);
    part += __shfl_xor(part, 32);
    if (lane < 16) sred[wid][lane] = part;
    __syncthreads();
    if (t < 16) {
      float sv = 0.f;
#pragma unroll
      for (int w = 0; w < 8; ++w) sv += sred[w][t];
      vsh[t] = sv / denom;
    }
    __syncthreads();
    if (t == 0) {
      float sn = 0.f;
#pragma unroll
      for (int oo = 0; oo < 16; ++oo) sn += vsh[oo] * vsh[oo];
      vsh[16] = sqrtf(sn) / (1.f + sn);
    }
    __syncthreads();
    if (it < 2) {
      float vo = vsh[o] * vsh[16];
#pragma unroll
      for (int k = 0; k < NREG; ++k) {
        float val = pri[k] * vo;
        val += __shfl_xor(val, 1);
        val += __shfl_xor(val, 2);
        val += __shfl_xor(val, 4);
        val += __shfl_xor(val, 8);
        if (o == 0) lg[k * 32 + rhi] += val;
      }
      __syncthreads();
    }
  }
  if (t < 16) out[((size_t)b * C + c) * 16 + t] = vsh[t] * vsh[16];
}

// ---------- fused classes + fc1: norms/softmax/argmax + sparse fc1 ----------
__global__ __launch_bounds__(256) void fc1cls_kernel(
    const float* __restrict__ v, const float* __restrict__ w,
    const float* __restrict__ bias, float* __restrict__ outc,
    float* __restrict__ out) {
  int n  = blockIdx.x * 256 + threadIdx.x;
  int b0 = blockIdx.y * 8;
  int t = threadIdx.x;
  __shared__ float vall[8][160];
  __shared__ float nrm[8][10];
  __shared__ int ams[8];
  for (int idx = t; idx < 1280; idx += 256) {
    int bb = idx / 160, j = idx - bb * 160;
    vall[bb][j] = v[(size_t)(b0 + bb) * 160 + j];
  }
  __syncthreads();
  if (t < 80) {
    int bb = t / 10, c = t - bb * 10;
    float sn = 0.f;
#pragma unroll
    for (int o = 0; o < 16; ++o) {
      float xv = vall[bb][c * 16 + o];
      sn += xv * xv;
    }
    nrm[bb][c] = sqrtf(sn);
  }
  __syncthreads();
  if (t < 8) {
    float m = nrm[t][0];
    int am = 0;
    for (int c = 1; c < 10; ++c)
      if (nrm[t][c] > m) { m = nrm[t][c]; am = c; }  // first-max
    ams[t] = am;
    if (blockIdx.x == 0) {
      float s = 0.f;
      float e[10];
      for (int c = 0; c < 10; ++c) { e[c] = __expf(nrm[t][c] - m); s += e[c]; }
      for (int c = 0; c < 10; ++c) outc[(b0 + t) * 10 + c] = e[c] / s;
    }
  }
  __syncthreads();
  float bv = bias[n];
#pragma unroll
  for (int bb = 0; bb < 8; ++bb) {
    int row0 = ams[bb] * 16;
    float acc = bv;
#pragma unroll
    for (int oo = 0; oo < 16; ++oo)
      acc += vall[bb][row0 + oo] * w[(size_t)(row0 + oo) * 1024 + n];
    out[(size_t)(b0 + bb) * 1024 + n] = fmaxf(acc, 0.f);
  }
}

// ---------- split-K FC: partial over K-chunk -> pbuf[kz][32][N] -------------
template <int K, int KCH>
__global__ __launch_bounds__(256) void fcsplit_kernel(
    const float* __restrict__ in, const float* __restrict__ w,
    float* __restrict__ pbuf, int N) {
  int n  = blockIdx.x * 256 + threadIdx.x;
  int b0 = blockIdx.y * 8;
  int k0 = blockIdx.z * KCH;
  __shared__ __align__(16) float inl[KCH * 8];  // [k][bb]
  for (int idx = threadIdx.x; idx < 8 * KCH; idx += 256) {
    int bb = idx / KCH, k = idx - bb * KCH;
    inl[k * 8 + bb] = in[(size_t)(b0 + bb) * K + k0 + k];
  }
  __syncthreads();
  float acc[8];
#pragma unroll
  for (int bb = 0; bb < 8; ++bb) acc[bb] = 0.f;
  for (int k = 0; k < KCH; ++k) {
    float wv = w[(size_t)(k0 + k) * N + n];
    const float4 i0 = *reinterpret_cast<const float4*>(&inl[k * 8]);
    const float4 i1 = *reinterpret_cast<const float4*>(&inl[k * 8 + 4]);
    acc[0] += i0.x * wv; acc[1] += i0.y * wv;
    acc[2] += i0.z * wv; acc[3] += i0.w * wv;
    acc[4] += i1.x * wv; acc[5] += i1.y * wv;
    acc[6] += i1.z * wv; acc[7] += i1.w * wv;
  }
#pragma unroll
  for (int bb = 0; bb < 8; ++bb)
    pbuf[((size_t)blockIdx.z * 32 + b0 + bb) * N + n] = acc[bb];
}

// ---------- combine partials + bias + activation ----------------------------
template <int KS, bool RELU, bool SIG>
__global__ void fccomb_kernel(const float* __restrict__ pbuf,
                              const float* __restrict__ bias,
                              float* __restrict__ out, int N) {
  int idx = blockIdx.x * 256 + threadIdx.x;  // b*N + n
  if (idx >= 32 * N) return;
  int b = idx / N, n = idx - b * N;
  float a = bias[n];
#pragma unroll
  for (int kz = 0; kz < KS; ++kz) a += pbuf[((size_t)kz * 32 + b) * N + n];
  if (RELU) a = fmaxf(a, 0.f);
  if (SIG)  a = 1.f / (1.f + __expf(-a));
  out[idx] = a;
}

// ---------------------------------------------------------------------------
extern "C" void kernel_launch(void* const* d_in, const int* in_sizes, int n_in,
                              void* d_out, int out_size, void* d_ws,
                              size_t ws_size, hipStream_t stream) {
  const float* x       = (const float*)d_in[0];
  const float* conv0_w = (const float*)d_in[1];
  const float* conv0_b = (const float*)d_in[2];
  const float* conv1_w = (const float*)d_in[3];
  const float* conv1_b = (const float*)d_in[4];
  const float* prim_w  = (const float*)d_in[5];
  const float* prim_b  = (const float*)d_in[6];
  const float* W1      = (const float*)d_in[7];
  const float* W2      = (const float*)d_in[8];
  const float* dec_w1  = (const float*)d_in[9];
  const float* dec_b1  = (const float*)d_in[10];
  const float* dec_w2  = (const float*)d_in[11];
  const float* dec_b2  = (const float*)d_in[12];
  const float* dec_w3  = (const float*)d_in[13];
  const float* dec_b3  = (const float*)d_in[14];
  float* out = (float*)d_out;

  // ---- persistent zone ----
  float* ws    = (float*)d_ws;
  float* caps  = ws;                    //   294,912 f  [32][1152][8]
  float* u     = caps + 294912;         //    32,768 f  [32][64][16]
  float* vc    = u + 32768;             //     5,120 f  [32][10][16]
  float* trans = vc + 5120 + 32;        // transient zone base

  // ---- transient zone: conv phase ----
  f16* wA    = (f16*)trans;             //  5,308,416 h [81][256][256]
  f16* wB    = wA + 5308416;            //  5,308,416 h (tap-81 over-read ok)
  f16* h0f   = wB + 5308416;            //  6,193,152 h [32][756][256]
  f16* h1f   = h0f + 6193152;           //  3,112,960 h [32][380][256]
  f16* part1 = h1f + 3112960;           // 12,582,912 h [4][32][384][256]
  float* part2 = (float*)part1;         //  3,145,728 f (alias part1)
  // ---- transient zone: routing phase ----
  f16* pri1  = (f16*)trans;             // 37,748,736 h [64][32][1152][16]
  // ---- transient zone: decoder phase ----
  float* d1  = trans;                   //    32,768 f
  float* d2  = d1 + 32768;              //    65,536 f
  float* pb2 = d2 + 65536;              //   262,144 f
  float* pb3 = pb2 + 262144;            // 1,048,576 f

  wprep_kernel<<<512, 256, 0, stream>>>(conv1_w, prim_w, wA, wB);

  conv0_kernel<<<dim3(NB, 8, 2), 256, 0, stream>>>(x, conv0_w, conv0_b, h0f);

  conv1_mfma<<<1024, 256, 0, stream>>>(h0f, wA, part1);
  comb1_kernel<<<1520, 256, 0, stream>>>(part1, conv1_b, h1f);

  prim_mfma<<<512, 256, 0, stream>>>(h1f, wB, part2);
  combsq_kernel<<<NB * 48, 256, 0, stream>>>(part2, prim_b, caps);

  priors1_kernel<<<dim3(64, 36), 256, 0, stream>>>(caps, W1, pri1);
  route1_kernel<<<dim3(64, NB), 512, 0, stream>>>(pri1, u);

  routing_kernel<64, 16>
      <<<dim3(10, NB), 512, 2 * 64 * sizeof(float), stream>>>(u, W2, vc);

  fc1cls_kernel<<<dim3(4, 4), 256, 0, stream>>>(vc, dec_w1, dec_b1, out, d1);

  fcsplit_kernel<1024, 256>
      <<<dim3(8, 4, 4), 256, 0, stream>>>(d1, dec_w2, pb2, 2048);
  fccomb_kernel<4, true, false>
      <<<256, 256, 0, stream>>>(pb2, dec_b2, d2, 2048);

  fcsplit_kernel<2048, 256>
      <<<dim3(16, 4, 8), 256, 0, stream>>>(d2, dec_w3, pb3, 4096);
  fccomb_kernel<8, false, true>
      <<<512, 256, 0, stream>>>(pb3, dec_b3, out + 320, 4096);
}